// Round 8
// baseline (126.094 us; speedup 1.0000x reference)
//
#include <hip/hip_runtime.h>

typedef __bf16 bf16;
typedef __bf16 bf16x4 __attribute__((ext_vector_type(4)));
typedef __bf16 bf16x8 __attribute__((ext_vector_type(8)));
typedef float  f32x4  __attribute__((ext_vector_type(4)));

#define CIN   256
#define KK    9
#define KDIM  2304
#define KITERS 72            // KDIM / 32
#define PXW   64             // pixels per WG
#define NSLOT 3              // ring of half-tap slots
#define SLOT_ELEMS (PXW * 128)   // 64 px x 128 ch = 16 KB bf16

// force a wave-uniform value into an SGPR
__device__ __forceinline__ float sread(float f) {
    return __builtin_bit_cast(float,
        __builtin_amdgcn_readfirstlane(__builtin_bit_cast(int, f)));
}
__device__ __forceinline__ int sreadi(int v) {
    return __builtin_amdgcn_readfirstlane(v);
}

// ---------------------------------------------------------------------------
// Fused prep: blocks [0,1024) transpose x -> channels-last bf16 xt;
//             blocks [1024,3328) pack weight -> MFMA-fragment-ordered wq:
//   wq[ ((m*72 + kt)*64 + lane)*8 + j ] = W[o=m*16+l16][k=kt*32+quad*8+j]
// ---------------------------------------------------------------------------
__global__ __launch_bounds__(256) void prep_k(const float* __restrict__ x,
                                              const float* __restrict__ w,
                                              bf16* __restrict__ xt,
                                              bf16* __restrict__ wq) {
    int bid = blockIdx.x;
    int tid = threadIdx.x;
    if (bid < 1024) {
        __shared__ bf16 tile[64][72];        // px-major; rows 144 B
        int pt = bid & 63, ct = (bid >> 6) & 3, b = bid >> 8;
        int lane = tid & 63, row = tid >> 6;
        const float* src = x + ((size_t)(b * 256 + ct * 64)) * 4096 + pt * 64;
        #pragma unroll
        for (int cc = row; cc < 64; cc += 4)
            tile[lane][cc] = (bf16)src[(size_t)cc * 4096 + lane];
        __syncthreads();
        bf16* dst = xt + ((size_t)(b * 4096 + pt * 64)) * 256 + ct * 64;
        int p = tid >> 3, j = tid & 7;
        #pragma unroll
        for (int pp = p; pp < 64; pp += 32)
            *reinterpret_cast<bf16x8*>(dst + (size_t)pp * 256 + j * 8) =
                *reinterpret_cast<const bf16x8*>(&tile[pp][j * 8]);
    } else {
        int idx  = (bid - 1024) * 256 + tid;   // < 589824
        int j    = idx & 7;
        int lane = (idx >> 3) & 63;
        int rest = idx >> 9;                   // m*72 + kt
        int kt   = rest % KITERS;
        int m    = rest / KITERS;
        int l16  = lane & 15;
        int quad = lane >> 4;
        int o    = m * 16 + l16;
        int k    = kt * 32 + quad * 8 + j;
        int tap  = k >> 8;
        int cc   = k & 255;
        wq[idx] = (bf16)w[(size_t)o * KDIM + cc * KK + tap];
    }
}

// ---------------------------------------------------------------------------
// Wave-specialized producer/consumer deformable GEMM.
// WG = 1024 thr (16 waves), PXW=64, grid 256 (1 WG/CU), XCD band swizzle.
// Producers (waves 0-7): sample 8 px/wave/tap, write half-tap slabs
//   (64px x 128ch, XOR-swizzled) into a ring of 3 LDS slots. Their gathers
//   live in producer vmcnt queues -> never drained by consumer waits.
// Consumers (waves 8-15): wave = M32 x N64 (m_t=2, n_t=4); JIT A-loads from
//   L2-resident wq; MFMA runs continuously, gather latency hidden by ring.
// Sync: monotonic ready/freed counters per slot (generation g = h/3):
//   producer of half-slab h waits freed[h%3] >= 8*(h/3), flags ready+=1 (x8
//   waves); consumer of h waits ready[h%3] >= 8*(h/3+1), flags freed+=1.
// No __syncthreads in the main loop -> no CU-wide lockstep.
// ---------------------------------------------------------------------------
__global__ __launch_bounds__(1024) void deform_gemm_k(
    const bf16*  __restrict__ xt,
    const float* __restrict__ off,
    const bf16*  __restrict__ wq,
    const float* __restrict__ bias,
    float*       __restrict__ out) {

    __shared__ bf16 S[NSLOT * SLOT_ELEMS];   // 49,152 B
    __shared__ int ready[NSLOT];
    __shared__ int freed[NSLOT];

    int tid   = threadIdx.x;
    int wavei = sreadi(tid >> 6);   // 0..15
    int lane  = tid & 63;
    int quad  = lane >> 4;
    int l16   = lane & 15;

    int bid   = blockIdx.x;                      // 0..255
    int pb    = ((bid & 7) << 5) | (bid >> 3);   // XCD-band pixel-block
    int pix0  = pb * PXW;
    int b     = pix0 >> 12;                      // WG-uniform batch
    int pimgb = pix0 & 4095;
    int obase = b * 73728;                       // scalar base into off[]

    if (tid < NSLOT) { ready[tid] = 0; freed[tid] = 0; }
    __syncthreads();

    if (wavei < 8) {
        // ======================= producer =======================
        int pw = wavei;                           // owns px pw*8 .. pw*8+7
        unsigned base = (unsigned)b * 1048576u + (unsigned)(lane * 4);
        for (int tap = 0; tap < KK; ++tap) {
            int ty = tap / 3 - 1;
            int tx = tap % 3 - 1;
            int h0 = 2 * tap,     s0 = h0 % 3, g0 = h0 / 3;
            int h1 = 2 * tap + 1, s1 = h1 % 3, g1 = h1 / 3;
            while (*(volatile int*)&freed[s0] < 8 * g0) __builtin_amdgcn_s_sleep(2);
            while (*(volatile int*)&freed[s1] < 8 * g1) __builtin_amdgcn_s_sleep(2);

            #pragma unroll
            for (int gq = 0; gq < 2; ++gq) {      // 2 groups of 4 px
                int u[4][4];        // SGPR element offsets within batch image
                float wt[4][4];     // SGPR bilinear weights
                #pragma unroll
                for (int i = 0; i < 4; ++i) {
                    int n    = pw * 8 + gq * 4 + i;
                    int pimg = pimgb + n;                          // scalar
                    float oy = off[obase + pimg + (2 * tap) * 4096];
                    float ox = off[obase + pimg + (2 * tap + 1) * 4096];
                    float py = (float)((pimg >> 6) + ty) + oy;
                    float px = (float)((pimg & 63) + tx) + ox;
                    float fy = floorf(py), fx = floorf(px);
                    int   y0 = (int)fy,    x0 = (int)fx;
                    float wy1 = py - fy, wx1 = px - fx;
                    float wy0 = 1.f - wy1, wx0 = 1.f - wx1;
                    wy0 = ((unsigned)y0       < 64u) ? wy0 : 0.f;
                    wy1 = ((unsigned)(y0 + 1) < 64u) ? wy1 : 0.f;
                    wx0 = ((unsigned)x0       < 64u) ? wx0 : 0.f;
                    wx1 = ((unsigned)(x0 + 1) < 64u) ? wx1 : 0.f;
                    int yc0 = min(max(y0, 0), 63), yc1 = min(max(y0 + 1, 0), 63);
                    int xc0 = min(max(x0, 0), 63), xc1 = min(max(x0 + 1, 0), 63);
                    u[i][0] = sreadi((yc0 * 64 + xc0) * 256);
                    u[i][1] = sreadi((yc0 * 64 + xc1) * 256);
                    u[i][2] = sreadi((yc1 * 64 + xc0) * 256);
                    u[i][3] = sreadi((yc1 * 64 + xc1) * 256);
                    wt[i][0] = sread(wy0 * wx0); wt[i][1] = sread(wy0 * wx1);
                    wt[i][2] = sread(wy1 * wx0); wt[i][3] = sread(wy1 * wx1);
                }
                bf16x4 v[4][4];
                #pragma unroll
                for (int i = 0; i < 4; ++i)
                    #pragma unroll
                    for (int j = 0; j < 4; ++j)
                        v[i][j] = *reinterpret_cast<const bf16x4*>(
                            xt + base + (unsigned)u[i][j]);
                #pragma unroll
                for (int i = 0; i < 4; ++i) {
                    float a0 = 0.f, a1 = 0.f, a2 = 0.f, a3 = 0.f;
                    #pragma unroll
                    for (int j = 0; j < 4; ++j) {
                        float wgt = wt[i][j];
                        a0 += wgt * (float)v[i][j][0];
                        a1 += wgt * (float)v[i][j][1];
                        a2 += wgt * (float)v[i][j][2];
                        a3 += wgt * (float)v[i][j][3];
                    }
                    bf16x4 sv;
                    sv[0] = (bf16)a0; sv[1] = (bf16)a1;
                    sv[2] = (bf16)a2; sv[3] = (bf16)a3;
                    int n    = pw * 8 + gq * 4 + i;
                    int slot = (lane >= 32) ? s1 : s0;   // lane's ch-half
                    int gw   = (lane & 31) >> 1;         // 8-ch granule 0..15
                    int gs   = (gw & 8) | ((gw ^ (n & 7)) & 7);  // XOR swizzle
                    *reinterpret_cast<bf16x4*>(
                        &S[slot * SLOT_ELEMS + n * 128 + gs * 8 + (lane & 1) * 4]) = sv;
                }
            }
            __threadfence_block();
            if (lane == 0) { atomicAdd(&ready[s0], 1); atomicAdd(&ready[s1], 1); }
        }
    } else {
        // ======================= consumer =======================
        int cw = wavei - 8;     // 0..7 -> mtiles 2cw, 2cw+1 (M32 per wave)
        f32x4 acc[2][4];
        #pragma unroll
        for (int mt = 0; mt < 2; ++mt)
            #pragma unroll
            for (int nt = 0; nt < 4; ++nt)
                acc[mt][nt] = (f32x4){0.f, 0.f, 0.f, 0.f};

        for (int h = 0; h < 2 * KK; ++h) {
            int s = h % 3, g = h / 3;
            int tap = h >> 1, kh = h & 1;
            while (*(volatile int*)&ready[s] < 8 * (g + 1)) __builtin_amdgcn_s_sleep(2);
            __threadfence_block();
            const bf16* sb = &S[s * SLOT_ELEMS];
            #pragma unroll
            for (int kki = 0; kki < 4; ++kki) {
                int kt = tap * 8 + kh * 4 + kki;
                const bf16* ap = wq +
                    ((size_t)(((2 * cw) * KITERS + kt) * 64 + lane)) * 8;
                bf16x8 a0 = *reinterpret_cast<const bf16x8*>(ap);
                bf16x8 a1 = *reinterpret_cast<const bf16x8*>(ap + (size_t)KITERS * 64 * 8);
                int gidx = kki * 4 + quad;           // granule 0..15 in half
                #pragma unroll
                for (int nt = 0; nt < 4; ++nt) {
                    int row = nt * 16 + l16;
                    int gs  = (gidx & 8) | ((gidx ^ (row & 7)) & 7);
                    bf16x8 bb = *reinterpret_cast<const bf16x8*>(
                        sb + row * 128 + gs * 8);
                    acc[0][nt] = __builtin_amdgcn_mfma_f32_16x16x32_bf16(a0, bb, acc[0][nt], 0, 0, 0);
                    acc[1][nt] = __builtin_amdgcn_mfma_f32_16x16x32_bf16(a1, bb, acc[1][nt], 0, 0, 0);
                }
            }
            __threadfence_block();
            if (lane == 0) atomicAdd(&freed[s], 1);
        }

        // ---- epilogue: C/D layout col=l16, row=quad*4+r ----
        #pragma unroll
        for (int nt = 0; nt < 4; ++nt) {
            int pg   = pix0 + nt * 16 + l16;
            int bb_  = pg >> 12;
            int pimg = pg & 4095;
            #pragma unroll
            for (int mt = 0; mt < 2; ++mt) {
                int m = (2 * cw + mt) * 16 + quad * 4;
                float* op = out + ((size_t)(bb_ * 256 + m)) * 4096 + pimg;
                #pragma unroll
                for (int r = 0; r < 4; ++r)
                    op[(size_t)r * 4096] = acc[mt][nt][r] + bias[m + r];
            }
        }
    }
}

// ---------------------------------------------------------------------------
extern "C" void kernel_launch(void* const* d_in, const int* in_sizes, int n_in,
                              void* d_out, int out_size, void* d_ws, size_t ws_size,
                              hipStream_t stream) {
    const float* x    = (const float*)d_in[0];   // [4,256,64,64]
    const float* off  = (const float*)d_in[1];   // [4,18,64,64]
    const float* w    = (const float*)d_in[2];   // [256,256,3,3]
    const float* bias = (const float*)d_in[3];   // [256]
    float* out = (float*)d_out;                  // [4,256,64,64]

    bf16* wq = (bf16*)d_ws;                               // 1,179,648 B
    bf16* xt = (bf16*)((char*)d_ws + (size_t)589824 * 2); // 8,388,608 B

    prep_k<<<3328, 256, 0, stream>>>(x, w, xt, wq);
    deform_gemm_k<<<256, 1024, 0, stream>>>(xt, off, wq, bias, out);
}

// Round 9
// 119.251 us; speedup vs baseline: 1.0574x; 1.0574x over previous
//
#include <hip/hip_runtime.h>

typedef __bf16 bf16;
typedef __bf16 bf16x4 __attribute__((ext_vector_type(4)));
typedef __bf16 bf16x8 __attribute__((ext_vector_type(8)));
typedef float  f32x4  __attribute__((ext_vector_type(4)));

#define CIN   256
#define KK    9
#define KDIM  2304
#define KITERS 72            // KDIM / 32
#define PXW   32             // pixels per WG

// force a wave-uniform value into an SGPR
__device__ __forceinline__ float sread(float f) {
    return __builtin_bit_cast(float,
        __builtin_amdgcn_readfirstlane(__builtin_bit_cast(int, f)));
}
__device__ __forceinline__ int sreadi(int v) {
    return __builtin_amdgcn_readfirstlane(v);
}

// ---------------------------------------------------------------------------
// Fused prep: blocks [0,1024) transpose x -> channels-last bf16 xt;
//             blocks [1024,3328) pack weight -> MFMA-fragment-ordered wq:
//   wq[ ((m*72 + kt)*64 + lane)*8 + j ] = W[o=m*16+l16][k=kt*32+quad*8+j]
// ---------------------------------------------------------------------------
__global__ __launch_bounds__(256) void prep_k(const float* __restrict__ x,
                                              const float* __restrict__ w,
                                              bf16* __restrict__ xt,
                                              bf16* __restrict__ wq) {
    int bid = blockIdx.x;
    int tid = threadIdx.x;
    if (bid < 1024) {
        __shared__ bf16 tile[64][72];        // px-major; rows 144 B
        int pt = bid & 63, ct = (bid >> 6) & 3, b = bid >> 8;
        int lane = tid & 63, row = tid >> 6;
        const float* src = x + ((size_t)(b * 256 + ct * 64)) * 4096 + pt * 64;
        #pragma unroll
        for (int cc = row; cc < 64; cc += 4)
            tile[lane][cc] = (bf16)src[(size_t)cc * 4096 + lane];
        __syncthreads();
        bf16* dst = xt + ((size_t)(b * 4096 + pt * 64)) * 256 + ct * 64;
        int p = tid >> 3, j = tid & 7;
        #pragma unroll
        for (int pp = p; pp < 64; pp += 32)
            *reinterpret_cast<bf16x8*>(dst + (size_t)pp * 256 + j * 8) =
                *reinterpret_cast<const bf16x8*>(&tile[pp][j * 8]);
    } else {
        int idx  = (bid - 1024) * 256 + tid;   // < 589824
        int j    = idx & 7;
        int lane = (idx >> 3) & 63;
        int rest = idx >> 9;                   // m*72 + kt
        int kt   = rest % KITERS;
        int m    = rest / KITERS;
        int l16  = lane & 15;
        int quad = lane >> 4;
        int o    = m * 16 + l16;
        int k    = kt * 32 + quad * 8 + j;
        int tap  = k >> 8;
        int cc   = k & 255;
        wq[idx] = (bf16)w[(size_t)o * KDIM + cc * KK + tap];
    }
}

// ---------------------------------------------------------------------------
// Fused sampling -> LDS -> MFMA GEMM, software-pipelined across taps.
// WG = 512 thr (8 waves), PXW=32, wave = M32 x N32, grid 512 (2 WG/CU).
// Per tap t: [A-half0 loads] [gathers(t+1) px0-1] [GEMM0] [A-half1]
//            [gathers px2-3] [GEMM1] [blend -> S[other]] [barrier].
// KEY ORDERING: A-loads issue BEFORE gathers. vmcnt retires in issue order
// (m135), so GEMM's waits on A drain only A — the 16 gathers for tap t+1
// stay in flight under the MFMA burst. (Round 4 had the order reversed,
// which drained the prefetch; that was the failure mode.)
// sched_barrier(0) x4/tap pins only load-issue order.
// S: double-buffered, XOR 16B-granule swizzle (gs = (g&24)|((g^(row&7))&7)):
// row stride 512 B == 0 mod banks, swizzle spreads; writes are permutations.
// XCD band swizzle kept (round 5: FETCH 33.5 -> 10.3 MB).
// ---------------------------------------------------------------------------
__global__ __launch_bounds__(512, 4) void deform_gemm_k(
    const bf16*  __restrict__ xt,
    const float* __restrict__ off,
    const bf16*  __restrict__ wq,
    const float* __restrict__ bias,
    float*       __restrict__ out) {

    __shared__ bf16 S[2][PXW * 256];   // 2 x 16 KB, swizzled granules

    int tid   = threadIdx.x;
    int wavei = sreadi(tid >> 6);   // 0..7
    int lane  = tid & 63;
    int quad  = lane >> 4;
    int l16   = lane & 15;

    int bid   = blockIdx.x;                      // 0..511
    int pb    = ((bid & 7) << 6) | (bid >> 3);   // XCD-band pixel-block
    int pix0  = pb * PXW;
    int b     = pix0 >> 12;                      // WG-uniform batch
    int pimgb = pix0 & 4095;
    int obase = b * 73728;                       // scalar base into off[]
    unsigned base = (unsigned)b * 1048576u + (unsigned)(lane * 4); // into xt[]

    f32x4 acc[2][2];
    #pragma unroll
    for (int mt = 0; mt < 2; ++mt)
        #pragma unroll
        for (int nt = 0; nt < 2; ++nt)
            acc[mt][nt] = (f32x4){0.f, 0.f, 0.f, 0.f};

    // ---- helpers (all call sites fully unrolled) ----
    auto load_offs = [&](int tap, float* oy, float* ox) {
        #pragma unroll
        for (int i = 0; i < 4; ++i) {
            int pimg = pimgb + wavei * 4 + i;             // scalar
            oy[i] = off[obase + pimg + (2 * tap) * 4096];       // s_load
            ox[i] = off[obase + pimg + (2 * tap + 1) * 4096];   // s_load
        }
    };

    auto gather_px = [&](int tap, int i, float oy, float ox,
                         bf16x4* vv, float* wv) {
        int pimg = pimgb + wavei * 4 + i;
        float py = (float)((pimg >> 6) + tap / 3 - 1) + oy;
        float px = (float)((pimg & 63) + tap % 3 - 1) + ox;
        float fy = floorf(py), fx = floorf(px);
        int   y0 = (int)fy,    x0 = (int)fx;
        float wy1 = py - fy, wx1 = px - fx;
        float wy0 = 1.f - wy1, wx0 = 1.f - wx1;
        wy0 = ((unsigned)y0       < 64u) ? wy0 : 0.f;
        wy1 = ((unsigned)(y0 + 1) < 64u) ? wy1 : 0.f;
        wx0 = ((unsigned)x0       < 64u) ? wx0 : 0.f;
        wx1 = ((unsigned)(x0 + 1) < 64u) ? wx1 : 0.f;
        int yc0 = min(max(y0, 0), 63), yc1 = min(max(y0 + 1, 0), 63);
        int xc0 = min(max(x0, 0), 63), xc1 = min(max(x0 + 1, 0), 63);
        int u0 = sreadi((yc0 * 64 + xc0) * 256);
        int u1 = sreadi((yc0 * 64 + xc1) * 256);
        int u2 = sreadi((yc1 * 64 + xc0) * 256);
        int u3 = sreadi((yc1 * 64 + xc1) * 256);
        wv[0] = sread(wy0 * wx0); wv[1] = sread(wy0 * wx1);
        wv[2] = sread(wy1 * wx0); wv[3] = sread(wy1 * wx1);
        vv[0] = *reinterpret_cast<const bf16x4*>(xt + base + (unsigned)u0);
        vv[1] = *reinterpret_cast<const bf16x4*>(xt + base + (unsigned)u1);
        vv[2] = *reinterpret_cast<const bf16x4*>(xt + base + (unsigned)u2);
        vv[3] = *reinterpret_cast<const bf16x4*>(xt + base + (unsigned)u3);
    };

    auto blend_px = [&](bf16* Sw, int i, const bf16x4* vv, const float* wv) {
        float a0 = 0.f, a1 = 0.f, a2 = 0.f, a3 = 0.f;
        #pragma unroll
        for (int j = 0; j < 4; ++j) {
            float wgt = wv[j];
            a0 += wgt * (float)vv[j][0];
            a1 += wgt * (float)vv[j][1];
            a2 += wgt * (float)vv[j][2];
            a3 += wgt * (float)vv[j][3];
        }
        bf16x4 sv;
        sv[0] = (bf16)a0; sv[1] = (bf16)a1;
        sv[2] = (bf16)a2; sv[3] = (bf16)a3;
        int n  = wavei * 4 + i;
        int gw = lane >> 1;
        int gs = (gw & 24) | ((gw ^ (n & 7)) & 7);   // XOR granule swizzle
        *reinterpret_cast<bf16x4*>(Sw + n * 256 + gs * 8 + (lane & 1) * 4) = sv;
    };

    auto load_a = [&](int tap, int h, bf16x8 a[2][4]) {
        #pragma unroll
        for (int mt = 0; mt < 2; ++mt)
            #pragma unroll
            for (int kk = 0; kk < 4; ++kk) {
                int kt = tap * 8 + h * 4 + kk;
                a[mt][kk] = *reinterpret_cast<const bf16x8*>(
                    wq + ((size_t)(((2 * wavei + mt) * KITERS + kt) * 64 + lane)) * 8);
            }
    };

    auto gemm_half = [&](const bf16* Sr, int h, bf16x8 a[2][4]) {
        #pragma unroll
        for (int kk = 0; kk < 4; ++kk) {
            int kki = h * 4 + kk;
            int g   = kki * 4 + quad;
            int gs  = (g & 24) | ((g ^ (l16 & 7)) & 7);
            bf16x8 b0 = *reinterpret_cast<const bf16x8*>(Sr + l16 * 256 + gs * 8);
            bf16x8 b1 = *reinterpret_cast<const bf16x8*>(Sr + (16 + l16) * 256 + gs * 8);
            acc[0][0] = __builtin_amdgcn_mfma_f32_16x16x32_bf16(a[0][kk], b0, acc[0][0], 0, 0, 0);
            acc[0][1] = __builtin_amdgcn_mfma_f32_16x16x32_bf16(a[0][kk], b1, acc[0][1], 0, 0, 0);
            acc[1][0] = __builtin_amdgcn_mfma_f32_16x16x32_bf16(a[1][kk], b0, acc[1][0], 0, 0, 0);
            acc[1][1] = __builtin_amdgcn_mfma_f32_16x16x32_bf16(a[1][kk], b1, acc[1][1], 0, 0, 0);
        }
    };

    // ---- prologue: sample tap 0 into S[0] ----
    {
        float oy[4], ox[4];
        load_offs(0, oy, ox);
        bf16x4 v[4][4]; float wv[4][4];
        #pragma unroll
        for (int i = 0; i < 4; ++i) gather_px(0, i, oy[i], ox[i], v[i], wv[i]);
        #pragma unroll
        for (int i = 0; i < 4; ++i) blend_px(&S[0][0], i, v[i], wv[i]);
    }
    __syncthreads();

    // ---- pipelined main loop: taps 0..7 compute, sample t+1 ----
    for (int t = 0; t < 8; ++t) {
        const bf16* Sr = &S[t & 1][0];
        bf16*       Sw = &S[(t & 1) ^ 1][0];
        float oy[4], ox[4];
        load_offs(t + 1, oy, ox);              // scalar, off critical path

        bf16x8 alo[2][4];
        load_a(t, 0, alo);                     // A first -> FIFO head
        __builtin_amdgcn_sched_barrier(0);
        bf16x4 v[4][4]; float wv[4][4];
        gather_px(t + 1, 0, oy[0], ox[0], v[0], wv[0]);
        gather_px(t + 1, 1, oy[1], ox[1], v[1], wv[1]);
        __builtin_amdgcn_sched_barrier(0);
        gemm_half(Sr, 0, alo);                 // waits drain A only

        bf16x8 ahi[2][4];
        load_a(t, 1, ahi);
        __builtin_amdgcn_sched_barrier(0);
        gather_px(t + 1, 2, oy[2], ox[2], v[2], wv[2]);
        gather_px(t + 1, 3, oy[3], ox[3], v[3], wv[3]);
        __builtin_amdgcn_sched_barrier(0);
        gemm_half(Sr, 1, ahi);

        #pragma unroll
        for (int i = 0; i < 4; ++i) blend_px(Sw, i, v[i], wv[i]);
        __syncthreads();
    }

    // ---- tap 8: GEMM only (S[0] holds tap-8 data) ----
    {
        const bf16* Sr = &S[0][0];
        bf16x8 alo[2][4], ahi[2][4];
        load_a(8, 0, alo);
        load_a(8, 1, ahi);
        gemm_half(Sr, 0, alo);
        gemm_half(Sr, 1, ahi);
    }

    // ---- epilogue: C/D layout col=l16, row=quad*4+r ----
    #pragma unroll
    for (int nt = 0; nt < 2; ++nt) {
        int pg   = pix0 + nt * 16 + l16;
        int bb   = pg >> 12;
        int pimg = pg & 4095;
        #pragma unroll
        for (int mt = 0; mt < 2; ++mt) {
            int m = (2 * wavei + mt) * 16 + quad * 4;
            float* op = out + ((size_t)(bb * 256 + m)) * 4096 + pimg;
            #pragma unroll
            for (int r = 0; r < 4; ++r)
                op[(size_t)r * 4096] = acc[mt][nt][r] + bias[m + r];
        }
    }
}

// ---------------------------------------------------------------------------
extern "C" void kernel_launch(void* const* d_in, const int* in_sizes, int n_in,
                              void* d_out, int out_size, void* d_ws, size_t ws_size,
                              hipStream_t stream) {
    const float* x    = (const float*)d_in[0];   // [4,256,64,64]
    const float* off  = (const float*)d_in[1];   // [4,18,64,64]
    const float* w    = (const float*)d_in[2];   // [256,256,3,3]
    const float* bias = (const float*)d_in[3];   // [256]
    float* out = (float*)d_out;                  // [4,256,64,64]

    bf16* wq = (bf16*)d_ws;                               // 1,179,648 B
    bf16* xt = (bf16*)((char*)d_ws + (size_t)589824 * 2); // 8,388,608 B

    prep_k<<<3328, 256, 0, stream>>>(x, w, xt, wq);
    deform_gemm_k<<<512, 512, 0, stream>>>(xt, off, wq, bias, out);
}

// Round 10
// 117.248 us; speedup vs baseline: 1.0754x; 1.0171x over previous
//
#include <hip/hip_runtime.h>

typedef __bf16 bf16;
typedef __bf16 bf16x4 __attribute__((ext_vector_type(4)));
typedef __bf16 bf16x8 __attribute__((ext_vector_type(8)));
typedef float  f32x4  __attribute__((ext_vector_type(4)));

#define CIN   256
#define KK    9
#define KDIM  2304
#define KITERS 72            // KDIM / 32
#define PXW   32             // pixels per WG

// force a wave-uniform value into an SGPR
__device__ __forceinline__ float sread(float f) {
    return __builtin_bit_cast(float,
        __builtin_amdgcn_readfirstlane(__builtin_bit_cast(int, f)));
}
__device__ __forceinline__ int sreadi(int v) {
    return __builtin_amdgcn_readfirstlane(v);
}

// ---------------------------------------------------------------------------
// Fused prep: blocks [0,1024) transpose x -> channels-last bf16 xt;
//             blocks [1024,3328) pack weight -> MFMA-fragment-ordered wq:
//   wq[ ((m*72 + kt)*64 + lane)*8 + j ] = W[o=m*16+l16][k=kt*32+quad*8+j]
// ---------------------------------------------------------------------------
__global__ __launch_bounds__(256) void prep_k(const float* __restrict__ x,
                                              const float* __restrict__ w,
                                              bf16* __restrict__ xt,
                                              bf16* __restrict__ wq) {
    int bid = blockIdx.x;
    int tid = threadIdx.x;
    if (bid < 1024) {
        __shared__ bf16 tile[64][72];        // px-major; rows 144 B
        int pt = bid & 63, ct = (bid >> 6) & 3, b = bid >> 8;
        int lane = tid & 63, row = tid >> 6;
        const float* src = x + ((size_t)(b * 256 + ct * 64)) * 4096 + pt * 64;
        #pragma unroll
        for (int cc = row; cc < 64; cc += 4)
            tile[lane][cc] = (bf16)src[(size_t)cc * 4096 + lane];
        __syncthreads();
        bf16* dst = xt + ((size_t)(b * 4096 + pt * 64)) * 256 + ct * 64;
        int p = tid >> 3, j = tid & 7;
        #pragma unroll
        for (int pp = p; pp < 64; pp += 32)
            *reinterpret_cast<bf16x8*>(dst + (size_t)pp * 256 + j * 8) =
                *reinterpret_cast<const bf16x8*>(&tile[pp][j * 8]);
    } else {
        int idx  = (bid - 1024) * 256 + tid;   // < 589824
        int j    = idx & 7;
        int lane = (idx >> 3) & 63;
        int rest = idx >> 9;                   // m*72 + kt
        int kt   = rest % KITERS;
        int m    = rest / KITERS;
        int l16  = lane & 15;
        int quad = lane >> 4;
        int o    = m * 16 + l16;
        int k    = kt * 32 + quad * 8 + j;
        int tap  = k >> 8;
        int cc   = k & 255;
        wq[idx] = (bf16)w[(size_t)o * KDIM + cc * KK + tap];
    }
}

// ---------------------------------------------------------------------------
// Fused sampling -> LDS -> MFMA GEMM, occupancy-maximized.
// WG = 1024 thr (16 waves), PXW=32, grid 512 -> 2 WG/CU = 32 waves/CU (100%).
// Wave = M16 (mtile=wavei) x N32 (2 ntiles), acc = 8 VGPR; samples 2 px/tap.
// Weight L2 traffic unchanged vs r6 (each mtile read once per WG, 604 MB);
// sampling totals unchanged; only LDS-read issue count doubles (headroom).
// Double-buffered S, ONE barrier per tap (tap t+2's writes to S[t&1] are
// ordered behind barrier t+1, which all waves pass only after gemm(t)).
// Tap rotation rot=((bid>>3)&1)*4 desyncs co-resident WGs' phase bursts
// (GEMM accumulates over taps -> order-invariant).
// XCD band swizzle kept (r5: FETCH 33.5 -> 10.3 MB); XOR 16B-granule LDS
// swizzle kept (write = permutation, read = 2-way alias = free).
// ---------------------------------------------------------------------------
__global__ __launch_bounds__(1024, 8) void deform_gemm_k(
    const bf16*  __restrict__ xt,
    const float* __restrict__ off,
    const bf16*  __restrict__ wq,
    const float* __restrict__ bias,
    float*       __restrict__ out) {

    __shared__ bf16 S[2][PXW * 256];   // 2 x 16 KB, swizzled granules

    int tid   = threadIdx.x;
    int wavei = sreadi(tid >> 6);   // 0..15
    int lane  = tid & 63;
    int quad  = lane >> 4;
    int l16   = lane & 15;

    int bid   = blockIdx.x;                      // 0..511
    int pb    = ((bid & 7) << 6) | (bid >> 3);   // XCD-band pixel-block
    int pix0  = pb * PXW;
    int b     = pix0 >> 12;                      // WG-uniform batch
    int pimgb = pix0 & 4095;
    int obase = b * 73728;                       // scalar base into off[]
    unsigned base = (unsigned)b * 1048576u + (unsigned)(lane * 4); // into xt[]
    int rot   = ((bid >> 3) & 1) * 4;            // co-resident WG desync

    f32x4 acc[2];
    acc[0] = (f32x4){0.f, 0.f, 0.f, 0.f};
    acc[1] = (f32x4){0.f, 0.f, 0.f, 0.f};

    for (int t = 0; t < KK; ++t) {
        int tap = t + rot; if (tap >= KK) tap -= KK;
        int ty = tap / 3 - 1;
        int tx = tap % 3 - 1;
        bf16* Sw = &S[t & 1][0];

        // ---- sampling: wave fills rows n = wavei*2, wavei*2+1 ----
        #pragma unroll
        for (int i = 0; i < 2; ++i) {
            int n    = wavei * 2 + i;
            int pimg = pimgb + n;                          // scalar
            float oy = off[obase + pimg + (2 * tap) * 4096];      // s_load
            float ox = off[obase + pimg + (2 * tap + 1) * 4096];  // s_load
            float py = (float)((pimg >> 6) + ty) + oy;
            float px = (float)((pimg & 63) + tx) + ox;
            float fy = floorf(py), fx = floorf(px);
            int   y0 = (int)fy,    x0 = (int)fx;
            float wy1 = py - fy, wx1 = px - fx;
            float wy0 = 1.f - wy1, wx0 = 1.f - wx1;
            wy0 = ((unsigned)y0       < 64u) ? wy0 : 0.f;
            wy1 = ((unsigned)(y0 + 1) < 64u) ? wy1 : 0.f;
            wx0 = ((unsigned)x0       < 64u) ? wx0 : 0.f;
            wx1 = ((unsigned)(x0 + 1) < 64u) ? wx1 : 0.f;
            int yc0 = min(max(y0, 0), 63), yc1 = min(max(y0 + 1, 0), 63);
            int xc0 = min(max(x0, 0), 63), xc1 = min(max(x0 + 1, 0), 63);
            int u0 = sreadi((yc0 * 64 + xc0) * 256);
            int u1 = sreadi((yc0 * 64 + xc1) * 256);
            int u2 = sreadi((yc1 * 64 + xc0) * 256);
            int u3 = sreadi((yc1 * 64 + xc1) * 256);
            float w0 = sread(wy0 * wx0), w1 = sread(wy0 * wx1);
            float w2 = sread(wy1 * wx0), w3 = sread(wy1 * wx1);
            bf16x4 v0 = *reinterpret_cast<const bf16x4*>(xt + base + (unsigned)u0);
            bf16x4 v1 = *reinterpret_cast<const bf16x4*>(xt + base + (unsigned)u1);
            bf16x4 v2 = *reinterpret_cast<const bf16x4*>(xt + base + (unsigned)u2);
            bf16x4 v3 = *reinterpret_cast<const bf16x4*>(xt + base + (unsigned)u3);
            float a0 = w0 * (float)v0[0] + w1 * (float)v1[0]
                     + w2 * (float)v2[0] + w3 * (float)v3[0];
            float a1 = w0 * (float)v0[1] + w1 * (float)v1[1]
                     + w2 * (float)v2[1] + w3 * (float)v3[1];
            float a2 = w0 * (float)v0[2] + w1 * (float)v1[2]
                     + w2 * (float)v2[2] + w3 * (float)v3[2];
            float a3 = w0 * (float)v0[3] + w1 * (float)v1[3]
                     + w2 * (float)v2[3] + w3 * (float)v3[3];
            bf16x4 sv;
            sv[0] = (bf16)a0; sv[1] = (bf16)a1;
            sv[2] = (bf16)a2; sv[3] = (bf16)a3;
            int gw = lane >> 1;
            int gs = (gw & 24) | ((gw ^ (n & 7)) & 7);   // XOR granule swizzle
            *reinterpret_cast<bf16x4*>(Sw + n * 256 + gs * 8 + (lane & 1) * 4) = sv;
        }
        __syncthreads();

        // ---- GEMM over this tap's k=256: wave = mtile wavei x N32 ----
        const bf16* Sr  = Sw;
        const bf16* ap0 = wq + ((size_t)((wavei * KITERS + tap * 8) * 64 + lane)) * 8;
        #pragma unroll
        for (int kki = 0; kki < 8; ++kki) {
            bf16x8 a = *reinterpret_cast<const bf16x8*>(ap0 + (size_t)kki * 512);
            int g  = kki * 4 + quad;
            int gs = (g & 24) | ((g ^ (l16 & 7)) & 7);
            bf16x8 b0 = *reinterpret_cast<const bf16x8*>(Sr + l16 * 256 + gs * 8);
            bf16x8 b1 = *reinterpret_cast<const bf16x8*>(Sr + (16 + l16) * 256 + gs * 8);
            acc[0] = __builtin_amdgcn_mfma_f32_16x16x32_bf16(a, b0, acc[0], 0, 0, 0);
            acc[1] = __builtin_amdgcn_mfma_f32_16x16x32_bf16(a, b1, acc[1], 0, 0, 0);
        }
        // no second barrier: next tap writes the OTHER buffer; re-write of
        // this buffer (t+2) is ordered behind barrier t+1.
    }

    // ---- epilogue: C/D layout col=l16, row=quad*4+r; mtile = wavei ----
    #pragma unroll
    for (int nt = 0; nt < 2; ++nt) {
        int pg   = pix0 + nt * 16 + l16;
        int bb   = pg >> 12;
        int pimg = pg & 4095;
        int m    = wavei * 16 + quad * 4;
        float* op = out + ((size_t)(bb * 256 + m)) * 4096 + pimg;
        #pragma unroll
        for (int r = 0; r < 4; ++r)
            op[(size_t)r * 4096] = acc[nt][r] + bias[m + r];
    }
}

// ---------------------------------------------------------------------------
extern "C" void kernel_launch(void* const* d_in, const int* in_sizes, int n_in,
                              void* d_out, int out_size, void* d_ws, size_t ws_size,
                              hipStream_t stream) {
    const float* x    = (const float*)d_in[0];   // [4,256,64,64]
    const float* off  = (const float*)d_in[1];   // [4,18,64,64]
    const float* w    = (const float*)d_in[2];   // [256,256,3,3]
    const float* bias = (const float*)d_in[3];   // [256]
    float* out = (float*)d_out;                  // [4,256,64,64]

    bf16* wq = (bf16*)d_ws;                               // 1,179,648 B
    bf16* xt = (bf16*)((char*)d_ws + (size_t)589824 * 2); // 8,388,608 B

    prep_k<<<3328, 256, 0, stream>>>(x, w, xt, wq);
    deform_gemm_k<<<512, 1024, 0, stream>>>(xt, off, wq, bias, out);
}